// Round 5
// baseline (90.862 us; speedup 1.0000x reference)
//
#include <hip/hip_runtime.h>
#include <cmath>

// Problem geometry (fixed by the reference):
static constexpr int BATCH = 2048;
static constexpr int K = 64 * 1024;   // T*H = 65536
static constexpr int K4 = K / 4;      // float4 count per row

typedef float f4 __attribute__((ext_vector_type(4)));  // clang-native vec4

// Workspace layout: [0] uint wmax_bits, [1] uint arrival counter, [256..) packed int8 qw (64 KiB)
static constexpr size_t WS_NEEDED = 256 + (size_t)K;   // 65792 bytes

// ---------------------------------------------------------------------------
// Fused weight prep: 32 blocks.
//   phase 1: each block computes its partial max|w|, atomicMax into ws[0]
//            (uint bit-pattern of non-negative float preserves order ->
//            exact, order-independent, deterministic).
//   sync:    device-scope fence + arrival counter; all 32 blocks are
//            co-resident (32 << 256 CUs) so the spin cannot deadlock.
//   phase 2: each block quantizes its 1/32 chunk of w to packed int8.
// ws[0..1] must be zeroed before launch (hipMemsetAsync in kernel_launch,
// inside the graph -> re-zeroed on every replay).
// ---------------------------------------------------------------------------
__global__ __launch_bounds__(256)
void wprep_kernel(const float* __restrict__ w,
                  unsigned int* __restrict__ ws_hdr,   // [0]=wmax_bits [1]=counter
                  unsigned int* __restrict__ qw) {
    const int tid = blockIdx.x * 256 + threadIdx.x;          // 8192 threads
    const f4* w4 = reinterpret_cast<const f4*>(w);

    // ---- phase 1: partial max over this block's 512 float4s ----
    float m = 0.0f;
#pragma unroll
    for (int r = 0; r < 2; ++r) {
        f4 v = w4[tid + r * 8192];
        m = fmaxf(m, fmaxf(fmaxf(fabsf(v.x), fabsf(v.y)),
                           fmaxf(fabsf(v.z), fabsf(v.w))));
    }
#pragma unroll
    for (int off = 32; off > 0; off >>= 1)
        m = fmaxf(m, __shfl_down(m, off, 64));
    if ((threadIdx.x & 63) == 0)
        atomicMax(&ws_hdr[0], __float_as_uint(m));
    __syncthreads();

    // ---- arrival + spin until all 32 blocks have contributed ----
    if (threadIdx.x == 0) {
        __threadfence();
        atomicAdd(&ws_hdr[1], 1u);
        while (__hip_atomic_load(&ws_hdr[1], __ATOMIC_ACQUIRE,
                                 __HIP_MEMORY_SCOPE_AGENT) < 32u) { }
    }
    __syncthreads();

    // ---- phase 2: quantize own chunk (512 float4s / block, 2 / thread) ----
    const float cw = __uint_as_float(
        __hip_atomic_load(&ws_hdr[0], __ATOMIC_ACQUIRE, __HIP_MEMORY_SCOPE_AGENT));
    const float iw = 127.0f / cw;
#pragma unroll
    for (int r = 0; r < 2; ++r) {
        int idx = tid + r * 8192;
        f4 v = w4[idx];                                   // L2-warm from phase 1
        int q0 = (int)rintf(v.x * iw), q1 = (int)rintf(v.y * iw);
        int q2 = (int)rintf(v.z * iw), q3 = (int)rintf(v.w * iw);
        qw[idx] = (unsigned int)((q0 & 0xff) | ((q1 & 0xff) << 8) |
                                 ((q2 & 0xff) << 16) | ((q3 & 0xff) << 24));
    }
}

// ---------------------------------------------------------------------------
// Kernel B: fused fake-quant GEMV + bias + tanh. One block per row.
// Deep manual unroll: 8 nontemporal x-float4 loads + 8 qw dwords issued
// back-to-back per outer iteration to maximize loads in flight (MLP).
// Integer-space accumulation (exact products), scales folded at the end.
// ---------------------------------------------------------------------------
__global__ __launch_bounds__(256)
void gemv_quant_tanh_kernel(const float* __restrict__ x,
                            const unsigned int* __restrict__ qw,
                            const float* __restrict__ bias,
                            const float* __restrict__ clip,
                            const unsigned int* __restrict__ ws_hdr,
                            float* __restrict__ out) {
    const int row = blockIdx.x;
    const int tid = threadIdx.x;

    const float cw = __uint_as_float(ws_hdr[0]);   // kernel-boundary visibility
    const float cx = fabsf(clip[0]);
    const float ix = 127.0f / cx;
    const float scale = (cx / 127.0f) * (cw / 127.0f);  // sx * sw

    const f4* xr = reinterpret_cast<const f4*>(x + (size_t)row * K);

    float acc = 0.0f;
    for (int outer = 0; outer < 8; ++outer) {
        const int base = outer * 2048 + tid;
        f4 xv[8];
        unsigned int qv[8];
#pragma unroll
        for (int u = 0; u < 8; ++u)
            xv[u] = __builtin_nontemporal_load(&xr[base + u * 256]);
#pragma unroll
        for (int u = 0; u < 8; ++u)
            qv[u] = qw[base + u * 256];
#pragma unroll
        for (int u = 0; u < 8; ++u) {
            f4 v = xv[u];
            unsigned int q = qv[u];
            float qx0 = rintf(__builtin_amdgcn_fmed3f(v.x, -cx, cx) * ix);
            float qx1 = rintf(__builtin_amdgcn_fmed3f(v.y, -cx, cx) * ix);
            float qx2 = rintf(__builtin_amdgcn_fmed3f(v.z, -cx, cx) * ix);
            float qx3 = rintf(__builtin_amdgcn_fmed3f(v.w, -cx, cx) * ix);
            float w0 = (float)((int)(q << 24) >> 24);
            float w1 = (float)((int)(q << 16) >> 24);
            float w2 = (float)((int)(q <<  8) >> 24);
            float w3 = (float)((int)q >> 24);
            acc = fmaf(qx0, w0, acc);
            acc = fmaf(qx1, w1, acc);
            acc = fmaf(qx2, w2, acc);
            acc = fmaf(qx3, w3, acc);
        }
    }

    // block reduction: wave64 shuffle then 4 partials through LDS
#pragma unroll
    for (int off = 32; off > 0; off >>= 1)
        acc += __shfl_down(acc, off, 64);
    __shared__ float sm[4];
    if ((tid & 63) == 0) sm[tid >> 6] = acc;
    __syncthreads();
    if (tid == 0) {
        float s = (sm[0] + sm[1]) + (sm[2] + sm[3]);
        out[row] = tanhf(fmaf(s, scale, bias[0]));
    }
}

// ---------------------------------------------------------------------------
// Fallback path (round-3 kernels) if ws_size is too small for the qw buffer.
// ---------------------------------------------------------------------------
__global__ __launch_bounds__(256)
void wmax_atomic_kernel(const float* __restrict__ w, unsigned int* __restrict__ wmax_bits) {
    const int tid = blockIdx.x * 256 + threadIdx.x;
    const f4* w4 = reinterpret_cast<const f4*>(w);
    float m = 0.0f;
#pragma unroll
    for (int r = 0; r < 2; ++r) {
        f4 v = w4[tid + r * 8192];
        m = fmaxf(m, fmaxf(fmaxf(fabsf(v.x), fabsf(v.y)),
                           fmaxf(fabsf(v.z), fabsf(v.w))));
    }
#pragma unroll
    for (int off = 32; off > 0; off >>= 1)
        m = fmaxf(m, __shfl_down(m, off, 64));
    if ((threadIdx.x & 63) == 0)
        atomicMax(wmax_bits, __float_as_uint(m));
}

__global__ __launch_bounds__(256)
void gemv_fallback_kernel(const float* __restrict__ x, const float* __restrict__ w,
                          const float* __restrict__ bias, const float* __restrict__ clip,
                          const unsigned int* __restrict__ wmax_bits,
                          float* __restrict__ out) {
    const int row = blockIdx.x;
    const int tid = threadIdx.x;
    const float cx = fabsf(clip[0]);
    const float ix = 127.0f / cx;
    const float cw = __uint_as_float(wmax_bits[0]);
    const float iw = 127.0f / cw;
    const float scale = (cx / 127.0f) * (cw / 127.0f);
    const f4* xr = reinterpret_cast<const f4*>(x + (size_t)row * K);
    const f4* w4 = reinterpret_cast<const f4*>(w);
    float acc = 0.0f;
#pragma unroll 4
    for (int i = tid; i < K4; i += 256) {
        f4 xv = __builtin_nontemporal_load(&xr[i]);
        f4 wv = w4[i];
        float qx0 = rintf(__builtin_amdgcn_fmed3f(xv.x, -cx, cx) * ix);
        float qx1 = rintf(__builtin_amdgcn_fmed3f(xv.y, -cx, cx) * ix);
        float qx2 = rintf(__builtin_amdgcn_fmed3f(xv.z, -cx, cx) * ix);
        float qx3 = rintf(__builtin_amdgcn_fmed3f(xv.w, -cx, cx) * ix);
        acc = fmaf(qx0, rintf(wv.x * iw), acc);
        acc = fmaf(qx1, rintf(wv.y * iw), acc);
        acc = fmaf(qx2, rintf(wv.z * iw), acc);
        acc = fmaf(qx3, rintf(wv.w * iw), acc);
    }
#pragma unroll
    for (int off = 32; off > 0; off >>= 1)
        acc += __shfl_down(acc, off, 64);
    __shared__ float sm[4];
    if ((tid & 63) == 0) sm[tid >> 6] = acc;
    __syncthreads();
    if (tid == 0) {
        float s = (sm[0] + sm[1]) + (sm[2] + sm[3]);
        out[row] = tanhf(fmaf(s, scale, bias[0]));
    }
}

extern "C" void kernel_launch(void* const* d_in, const int* in_sizes, int n_in,
                              void* d_out, int out_size, void* d_ws, size_t ws_size,
                              hipStream_t stream) {
    const float* x    = (const float*)d_in[0];  // hidden_states [2048,64,1024]
    const float* w    = (const float*)d_in[1];  // weight [1, 65536]
    const float* bias = (const float*)d_in[2];  // [1]
    const float* clip = (const float*)d_in[3];  // scalar
    float* out = (float*)d_out;                 // [2048] fp32

    if (ws_size >= WS_NEEDED) {
        unsigned int* ws_hdr = (unsigned int*)d_ws;                   // [0]=max [1]=counter
        unsigned int* qw = (unsigned int*)((char*)d_ws + 256);        // 64 KiB
        (void)hipMemsetAsync(ws_hdr, 0, 2 * sizeof(unsigned int), stream);
        wprep_kernel<<<32, 256, 0, stream>>>(w, ws_hdr, qw);
        gemv_quant_tanh_kernel<<<BATCH, 256, 0, stream>>>(x, qw, bias, clip, ws_hdr, out);
    } else {
        unsigned int* wmax_bits = (unsigned int*)d_ws;
        (void)hipMemsetAsync(wmax_bits, 0, sizeof(unsigned int), stream);
        wmax_atomic_kernel<<<32, 256, 0, stream>>>(w, wmax_bits);
        gemv_fallback_kernel<<<BATCH, 256, 0, stream>>>(x, w, bias, clip, wmax_bits, out);
    }
}

// Round 6
// 85.015 us; speedup vs baseline: 1.0688x; 1.0688x over previous
//
#include <hip/hip_runtime.h>
#include <cmath>

// Problem geometry (fixed by the reference):
static constexpr int BATCH = 2048;
static constexpr int K = 64 * 1024;   // T*H = 65536
static constexpr int K4 = K / 4;      // float4 count per row

typedef float f4 __attribute__((ext_vector_type(4)));  // clang-native vec4

// Workspace layout: [0] float cw; [256..65792) packed int8 qw (64 KiB)
static constexpr size_t WS_NEEDED = 256 + (size_t)K;   // 65792 bytes

// ---------------------------------------------------------------------------
// Kernel P: single prep dispatch, 32 blocks, NO cross-block dependency.
// Every block redundantly computes the FULL max|w| (256 KiB; L2-hot after
// the first block touches it) -> identical bit-exact cw in all blocks
// (max is order-independent). Each block then quantizes its own 1/32 chunk
// of w to packed int8 and writes cw to ws[0] (same value from every block).
// No memset, no atomics, no spin.
// ---------------------------------------------------------------------------
__global__ __launch_bounds__(256)
void wprep_kernel(const float* __restrict__ w,
                  float* __restrict__ cw_out,
                  unsigned int* __restrict__ qw) {
    const int t = threadIdx.x;
    const f4* w4 = reinterpret_cast<const f4*>(w);

    // ---- full max over all 16384 float4s (64 per thread, coalesced) ----
    float m = 0.0f;
#pragma unroll 8
    for (int i = t; i < K4; i += 256) {
        f4 v = w4[i];
        m = fmaxf(m, fmaxf(fmaxf(fabsf(v.x), fabsf(v.y)),
                           fmaxf(fabsf(v.z), fabsf(v.w))));
    }
#pragma unroll
    for (int off = 32; off > 0; off >>= 1)
        m = fmaxf(m, __shfl_down(m, off, 64));
    __shared__ float sm[4];
    if ((t & 63) == 0) sm[t >> 6] = m;
    __syncthreads();
    const float cw = fmaxf(fmaxf(sm[0], sm[1]), fmaxf(sm[2], sm[3]));

    if (t == 0) cw_out[blockIdx.x == 0 ? 0 : 0] = cw;   // all blocks write same value

    // ---- quantize own chunk (512 float4s / block, 2 / thread, L2-warm) ----
    const float iw = 127.0f / cw;
    const int tid = blockIdx.x * 256 + t;
#pragma unroll
    for (int r = 0; r < 2; ++r) {
        int idx = tid + r * 8192;
        f4 v = w4[idx];
        int q0 = (int)rintf(v.x * iw), q1 = (int)rintf(v.y * iw);
        int q2 = (int)rintf(v.z * iw), q3 = (int)rintf(v.w * iw);
        qw[idx] = (unsigned int)((q0 & 0xff) | ((q1 & 0xff) << 8) |
                                 ((q2 & 0xff) << 16) | ((q3 & 0xff) << 24));
    }
}

// ---------------------------------------------------------------------------
// Kernel B (unchanged from round 4 = best): fused fake-quant GEMV + bias +
// tanh. One block per row. Deep manual unroll: 8 nontemporal x-float4 loads
// + 8 qw dwords issued back-to-back per outer iteration (MLP). Integer-space
// accumulation (exact products <= 127^2), scales folded once at the end.
// ---------------------------------------------------------------------------
__global__ __launch_bounds__(256)
void gemv_quant_tanh_kernel(const float* __restrict__ x,
                            const unsigned int* __restrict__ qw,
                            const float* __restrict__ bias,
                            const float* __restrict__ clip,
                            const float* __restrict__ cw_in,
                            float* __restrict__ out) {
    const int row = blockIdx.x;
    const int tid = threadIdx.x;

    const float cw = cw_in[0];
    const float cx = fabsf(clip[0]);
    const float ix = 127.0f / cx;
    const float scale = (cx / 127.0f) * (cw / 127.0f);  // sx * sw

    const f4* xr = reinterpret_cast<const f4*>(x + (size_t)row * K);

    float acc = 0.0f;
    for (int outer = 0; outer < 8; ++outer) {
        const int base = outer * 2048 + tid;
        f4 xv[8];
        unsigned int qv[8];
#pragma unroll
        for (int u = 0; u < 8; ++u)
            xv[u] = __builtin_nontemporal_load(&xr[base + u * 256]);
#pragma unroll
        for (int u = 0; u < 8; ++u)
            qv[u] = qw[base + u * 256];
#pragma unroll
        for (int u = 0; u < 8; ++u) {
            f4 v = xv[u];
            unsigned int q = qv[u];
            float qx0 = rintf(__builtin_amdgcn_fmed3f(v.x, -cx, cx) * ix);
            float qx1 = rintf(__builtin_amdgcn_fmed3f(v.y, -cx, cx) * ix);
            float qx2 = rintf(__builtin_amdgcn_fmed3f(v.z, -cx, cx) * ix);
            float qx3 = rintf(__builtin_amdgcn_fmed3f(v.w, -cx, cx) * ix);
            float w0 = (float)((int)(q << 24) >> 24);
            float w1 = (float)((int)(q << 16) >> 24);
            float w2 = (float)((int)(q <<  8) >> 24);
            float w3 = (float)((int)q >> 24);
            acc = fmaf(qx0, w0, acc);
            acc = fmaf(qx1, w1, acc);
            acc = fmaf(qx2, w2, acc);
            acc = fmaf(qx3, w3, acc);
        }
    }

    // block reduction: wave64 shuffle then 4 partials through LDS
#pragma unroll
    for (int off = 32; off > 0; off >>= 1)
        acc += __shfl_down(acc, off, 64);
    __shared__ float sm[4];
    if ((tid & 63) == 0) sm[tid >> 6] = acc;
    __syncthreads();
    if (tid == 0) {
        float s = (sm[0] + sm[1]) + (sm[2] + sm[3]);
        out[row] = tanhf(fmaf(s, scale, bias[0]));
    }
}

// ---------------------------------------------------------------------------
// Fallback path if ws_size is too small for the qw buffer.
// ---------------------------------------------------------------------------
__global__ __launch_bounds__(256)
void wmax_atomic_kernel(const float* __restrict__ w, unsigned int* __restrict__ wmax_bits) {
    const int tid = blockIdx.x * 256 + threadIdx.x;
    const f4* w4 = reinterpret_cast<const f4*>(w);
    float m = 0.0f;
#pragma unroll
    for (int r = 0; r < 2; ++r) {
        f4 v = w4[tid + r * 8192];
        m = fmaxf(m, fmaxf(fmaxf(fabsf(v.x), fabsf(v.y)),
                           fmaxf(fabsf(v.z), fabsf(v.w))));
    }
#pragma unroll
    for (int off = 32; off > 0; off >>= 1)
        m = fmaxf(m, __shfl_down(m, off, 64));
    if ((threadIdx.x & 63) == 0)
        atomicMax(wmax_bits, __float_as_uint(m));
}

__global__ __launch_bounds__(256)
void gemv_fallback_kernel(const float* __restrict__ x, const float* __restrict__ w,
                          const float* __restrict__ bias, const float* __restrict__ clip,
                          const unsigned int* __restrict__ wmax_bits,
                          float* __restrict__ out) {
    const int row = blockIdx.x;
    const int tid = threadIdx.x;
    const float cx = fabsf(clip[0]);
    const float ix = 127.0f / cx;
    const float cw = __uint_as_float(wmax_bits[0]);
    const float iw = 127.0f / cw;
    const float scale = (cx / 127.0f) * (cw / 127.0f);
    const f4* xr = reinterpret_cast<const f4*>(x + (size_t)row * K);
    const f4* w4 = reinterpret_cast<const f4*>(w);
    float acc = 0.0f;
#pragma unroll 4
    for (int i = tid; i < K4; i += 256) {
        f4 xv = __builtin_nontemporal_load(&xr[i]);
        f4 wv = w4[i];
        float qx0 = rintf(__builtin_amdgcn_fmed3f(xv.x, -cx, cx) * ix);
        float qx1 = rintf(__builtin_amdgcn_fmed3f(xv.y, -cx, cx) * ix);
        float qx2 = rintf(__builtin_amdgcn_fmed3f(xv.z, -cx, cx) * ix);
        float qx3 = rintf(__builtin_amdgcn_fmed3f(xv.w, -cx, cx) * ix);
        acc = fmaf(qx0, rintf(wv.x * iw), acc);
        acc = fmaf(qx1, rintf(wv.y * iw), acc);
        acc = fmaf(qx2, rintf(wv.z * iw), acc);
        acc = fmaf(qx3, rintf(wv.w * iw), acc);
    }
#pragma unroll
    for (int off = 32; off > 0; off >>= 1)
        acc += __shfl_down(acc, off, 64);
    __shared__ float sm[4];
    if ((tid & 63) == 0) sm[tid >> 6] = acc;
    __syncthreads();
    if (tid == 0) {
        float s = (sm[0] + sm[1]) + (sm[2] + sm[3]);
        out[row] = tanhf(fmaf(s, scale, bias[0]));
    }
}

extern "C" void kernel_launch(void* const* d_in, const int* in_sizes, int n_in,
                              void* d_out, int out_size, void* d_ws, size_t ws_size,
                              hipStream_t stream) {
    const float* x    = (const float*)d_in[0];  // hidden_states [2048,64,1024]
    const float* w    = (const float*)d_in[1];  // weight [1, 65536]
    const float* bias = (const float*)d_in[2];  // [1]
    const float* clip = (const float*)d_in[3];  // scalar
    float* out = (float*)d_out;                 // [2048] fp32

    if (ws_size >= WS_NEEDED) {
        float* cw = (float*)d_ws;                                     // 1 float
        unsigned int* qw = (unsigned int*)((char*)d_ws + 256);        // 64 KiB
        wprep_kernel<<<32, 256, 0, stream>>>(w, cw, qw);
        gemv_quant_tanh_kernel<<<BATCH, 256, 0, stream>>>(x, qw, bias, clip, cw, out);
    } else {
        unsigned int* wmax_bits = (unsigned int*)d_ws;
        (void)hipMemsetAsync(wmax_bits, 0, sizeof(unsigned int), stream);
        wmax_atomic_kernel<<<32, 256, 0, stream>>>(w, wmax_bits);
        gemv_fallback_kernel<<<BATCH, 256, 0, stream>>>(x, w, bias, clip, wmax_bits, out);
    }
}